// Round 1
// baseline (669.185 us; speedup 1.0000x reference)
//
#include <hip/hip_runtime.h>

typedef _Float16 half8 __attribute__((ext_vector_type(8)));
typedef float f32x4 __attribute__((ext_vector_type(4)));

#define M_DIM 8192
#define N_DIM 4096
#define K_DIM 4096
#define BM 128
#define BN 128
#define BK 64
#define NT (K_DIM / BK)

__global__ __launch_bounds__(256, 2)
void w8a16_gemm(const float* __restrict__ A,
                const void* __restrict__ Wv,
                const float* __restrict__ scales,
                const float* __restrict__ bias,
                float* __restrict__ out) {
    __shared__ char smem[2 * BM * BK * 2];   // A half-tile 16KB + B half-tile 16KB
    char* Ash = smem;
    char* Bsh = smem + BM * BK * 2;

    // ---- probe weight element width: int32 buffer or raw int8? ----
    // If device buffer is int32, every word is in [-128,127]. If raw int8,
    // words are random 32-bit values; P(16 words all in range) ~ 0.
    const int* wprobe = (const int*)Wv;
    bool wi32 = true;
#pragma unroll
    for (int i = 0; i < 16; ++i) {
        int v = wprobe[i];
        wi32 = wi32 && (v >= -128 && v <= 127);
    }

    const int tid  = threadIdx.x;
    const int lane = tid & 63;
    const int wv   = tid >> 6;        // wave id 0..3
    const int wm   = wv >> 1;         // wave row 0..1
    const int wn   = wv & 1;          // wave col 0..1
    const int r16  = lane & 15;
    const int kq   = lane >> 4;       // 0..3
    const int swzl = (r16 & 7) << 4;  // per-lane LDS XOR swizzle

    // ---- XCD-aware bijective block swizzle (2048 % 8 == 0) ----
    int bid = blockIdx.x;
    int swz = (bid & 7) * 256 + (bid >> 3);
    const int NBN = N_DIM / BN;       // 32
    int bm = swz / NBN;
    int bn = swz % NBN;

    const int row_a0 = bm * BM;
    const int row_b0 = bn * BN;

    // staging chunk coords: 1024 chunks of 8 elems per tile, 4 per thread
    int cr[4], cc[4];
#pragma unroll
    for (int i = 0; i < 4; ++i) {
        int c = tid + 256 * i;
        cr[i] = c >> 3;
        cc[i] = (c & 7) << 3;
    }

    float4 pa[8];
    int4   pbi[8];
    uint2  pb8[4];

    auto load_tile = [&](int kt) {
        int k0 = kt * BK;
#pragma unroll
        for (int i = 0; i < 4; ++i) {
            const float* p = A + (size_t)(row_a0 + cr[i]) * K_DIM + k0 + cc[i];
            pa[2 * i]     = *(const float4*)p;
            pa[2 * i + 1] = *(const float4*)(p + 4);
        }
        if (wi32) {
            const int* w = (const int*)Wv;
#pragma unroll
            for (int i = 0; i < 4; ++i) {
                const int* p = w + (size_t)(row_b0 + cr[i]) * K_DIM + k0 + cc[i];
                pbi[2 * i]     = *(const int4*)p;
                pbi[2 * i + 1] = *(const int4*)(p + 4);
            }
        } else {
            const signed char* w = (const signed char*)Wv;
#pragma unroll
            for (int i = 0; i < 4; ++i) {
                const signed char* p = w + (size_t)(row_b0 + cr[i]) * K_DIM + k0 + cc[i];
                pb8[i] = *(const uint2*)p;
            }
        }
    };

    auto write_lds = [&]() {
#pragma unroll
        for (int i = 0; i < 4; ++i) {
            int off = (cr[i] * 128 + cc[i] * 2) ^ ((cr[i] & 7) << 4);
            half8 h;
            h[0] = (_Float16)pa[2 * i].x;
            h[1] = (_Float16)pa[2 * i].y;
            h[2] = (_Float16)pa[2 * i].z;
            h[3] = (_Float16)pa[2 * i].w;
            h[4] = (_Float16)pa[2 * i + 1].x;
            h[5] = (_Float16)pa[2 * i + 1].y;
            h[6] = (_Float16)pa[2 * i + 1].z;
            h[7] = (_Float16)pa[2 * i + 1].w;
            *(half8*)(Ash + off) = h;

            half8 g;
            if (wi32) {
                g[0] = (_Float16)pbi[2 * i].x;
                g[1] = (_Float16)pbi[2 * i].y;
                g[2] = (_Float16)pbi[2 * i].z;
                g[3] = (_Float16)pbi[2 * i].w;
                g[4] = (_Float16)pbi[2 * i + 1].x;
                g[5] = (_Float16)pbi[2 * i + 1].y;
                g[6] = (_Float16)pbi[2 * i + 1].z;
                g[7] = (_Float16)pbi[2 * i + 1].w;
            } else {
                unsigned x = pb8[i].x, y = pb8[i].y;
                g[0] = (_Float16)(int)(signed char)(x & 0xff);
                g[1] = (_Float16)(int)(signed char)((x >> 8) & 0xff);
                g[2] = (_Float16)(int)(signed char)((x >> 16) & 0xff);
                g[3] = (_Float16)(int)(signed char)(x >> 24);
                g[4] = (_Float16)(int)(signed char)(y & 0xff);
                g[5] = (_Float16)(int)(signed char)((y >> 8) & 0xff);
                g[6] = (_Float16)(int)(signed char)((y >> 16) & 0xff);
                g[7] = (_Float16)(int)(signed char)(y >> 24);
            }
            *(half8*)(Bsh + off) = g;
        }
    };

    f32x4 acc[4][4] = {};

    auto compute = [&]() {
#pragma unroll
        for (int ks = 0; ks < 2; ++ks) {
            half8 af[4], bf[4];
#pragma unroll
            for (int m = 0; m < 4; ++m) {
                int row = wm * 64 + m * 16 + r16;
                af[m] = *(const half8*)(Ash + ((row * 128 + ks * 64 + kq * 16) ^ swzl));
            }
#pragma unroll
            for (int n = 0; n < 4; ++n) {
                int row = wn * 64 + n * 16 + r16;
                bf[n] = *(const half8*)(Bsh + ((row * 128 + ks * 64 + kq * 16) ^ swzl));
            }
#pragma unroll
            for (int m = 0; m < 4; ++m)
#pragma unroll
                for (int n = 0; n < 4; ++n)
                    acc[m][n] = __builtin_amdgcn_mfma_f32_16x16x32_f16(af[m], bf[n], acc[m][n], 0, 0, 0);
        }
    };

    load_tile(0);
#pragma unroll 1
    for (int kt = 0; kt < NT; ++kt) {
        if (kt) __syncthreads();
        write_lds();
        __syncthreads();
        if (kt + 1 < NT) load_tile(kt + 1);
        compute();
    }

    // ---- epilogue: scale + bias, fp32 out ----
#pragma unroll
    for (int n = 0; n < 4; ++n) {
        int col = row_b0 + wn * 64 + n * 16 + r16;
        float sc = scales[col];
        float bs = bias[col];
#pragma unroll
        for (int m = 0; m < 4; ++m) {
            int row0 = row_a0 + wm * 64 + m * 16 + kq * 4;
#pragma unroll
            for (int j = 0; j < 4; ++j) {
                out[(size_t)(row0 + j) * N_DIM + col] = acc[m][n][j] * sc + bs;
            }
        }
    }
}

extern "C" void kernel_launch(void* const* d_in, const int* in_sizes, int n_in,
                              void* d_out, int out_size, void* d_ws, size_t ws_size,
                              hipStream_t stream) {
    const float* A      = (const float*)d_in[0];
    const void*  W      = d_in[1];
    const float* scales = (const float*)d_in[2];
    const float* bias   = (const float*)d_in[3];
    float*       out    = (float*)d_out;

    dim3 grid((M_DIM / BM) * (N_DIM / BN));  // 64*32 = 2048
    dim3 block(256);
    hipLaunchKernelGGL(w8a16_gemm, grid, block, 0, stream, A, W, scales, bias, out);
}

// Round 2
// 347.547 us; speedup vs baseline: 1.9255x; 1.9255x over previous
//
#include <hip/hip_runtime.h>
#include <stdint.h>

typedef _Float16 half8 __attribute__((ext_vector_type(8)));
typedef float f32x4 __attribute__((ext_vector_type(4)));

#define M_DIM 8192
#define N_DIM 4096
#define K_DIM 4096
#define BM 128
#define BN 128
#define BK 64
#define NT (K_DIM / BK)            // 64
#define TILE_BYTES (BM * BK * 2)   // 16384

#define GLOAD_LDS16(g, l)                                        \
    __builtin_amdgcn_global_load_lds(                            \
        (const __attribute__((address_space(1))) uint32_t*)(g),  \
        (__attribute__((address_space(3))) uint32_t*)(l), 16, 0, 0)

// swizzled in-tile byte offset for element (r, c): r in [0,128), c in [0,64)
// XOR of byte bits [4:6] with row&7 -> per-wave ds_read_b128 spreads 8 lanes
// per 16B slot (uniform across 32 banks).
__device__ __forceinline__ int swz_off(int r, int c) {
    return (r * 128 + c * 2) ^ ((r & 7) << 4);
}

// ---------------- prep: A fp32 -> fp16, packed+swizzled tiles ----------------
__global__ __launch_bounds__(256)
void prep_a(const float* __restrict__ A, _Float16* __restrict__ Apack) {
    int g = blockIdx.x * 256 + threadIdx.x;    // 4,194,304 chunks of 8
    int r = g >> 9;                            // row 0..8191  (512 chunks/row)
    int c = (g & 511) << 3;                    // col 0..4088 step 8
    const float4* p = (const float4*)(A + (size_t)r * K_DIM + c);
    float4 a0 = p[0], a1 = p[1];
    half8 h;
    h[0] = (_Float16)a0.x; h[1] = (_Float16)a0.y;
    h[2] = (_Float16)a0.z; h[3] = (_Float16)a0.w;
    h[4] = (_Float16)a1.x; h[5] = (_Float16)a1.y;
    h[6] = (_Float16)a1.z; h[7] = (_Float16)a1.w;
    int bm = r >> 7, rl = r & 127, kt = c >> 6, cl = c & 63;
    char* dst = (char*)Apack + (size_t)(bm * NT + kt) * TILE_BYTES + swz_off(rl, cl);
    *(half8*)dst = h;
}

// ---------------- prep: W int -> fp16, packed+swizzled tiles ----------------
__global__ __launch_bounds__(256)
void prep_w(const void* __restrict__ Wv, _Float16* __restrict__ Wpack) {
    // probe element width: int32 buffer or raw int8?
    const int* wp = (const int*)Wv;
    bool wi32 = true;
#pragma unroll
    for (int i = 0; i < 16; ++i) {
        int v = wp[i];
        wi32 = wi32 && (v >= -128 && v <= 127);
    }
    int g = blockIdx.x * 256 + threadIdx.x;    // 2,097,152 chunks of 8
    int r = g >> 9;                            // row 0..4095
    int c = (g & 511) << 3;
    half8 h;
    if (wi32) {
        const int4* p = (const int4*)((const int*)Wv + (size_t)r * K_DIM + c);
        int4 w0 = p[0], w1 = p[1];
        h[0] = (_Float16)w0.x; h[1] = (_Float16)w0.y;
        h[2] = (_Float16)w0.z; h[3] = (_Float16)w0.w;
        h[4] = (_Float16)w1.x; h[5] = (_Float16)w1.y;
        h[6] = (_Float16)w1.z; h[7] = (_Float16)w1.w;
    } else {
        const signed char* p = (const signed char*)Wv + (size_t)r * K_DIM + c;
        uint2 u = *(const uint2*)p;
        unsigned x = u.x, y = u.y;
        h[0] = (_Float16)(int)(signed char)(x & 0xff);
        h[1] = (_Float16)(int)(signed char)((x >> 8) & 0xff);
        h[2] = (_Float16)(int)(signed char)((x >> 16) & 0xff);
        h[3] = (_Float16)(int)(signed char)(x >> 24);
        h[4] = (_Float16)(int)(signed char)(y & 0xff);
        h[5] = (_Float16)(int)(signed char)((y >> 8) & 0xff);
        h[6] = (_Float16)(int)(signed char)((y >> 16) & 0xff);
        h[7] = (_Float16)(int)(signed char)(y >> 24);
    }
    int bn = r >> 7, rl = r & 127, kt = c >> 6, cl = c & 63;
    char* dst = (char*)Wpack + (size_t)(bn * NT + kt) * TILE_BYTES + swz_off(rl, cl);
    *(half8*)dst = h;
}

// ---------------- main GEMM: m97 structure, global_load_lds staging ----------------
__global__ __launch_bounds__(256, 3)
void w8a16_gemm2(const _Float16* __restrict__ Apack,
                 const _Float16* __restrict__ Wpack,
                 const float* __restrict__ scales,
                 const float* __restrict__ bias,
                 float* __restrict__ out) {
    __shared__ char smem[2 * TILE_BYTES];     // 32 KiB
    char* Ash = smem;
    char* Bsh = smem + TILE_BYTES;

    const int tid  = threadIdx.x;
    const int lane = tid & 63;
    const int wv   = tid >> 6;
    const int wm   = wv >> 1;
    const int wn   = wv & 1;
    const int r16  = lane & 15;
    const int kq   = lane >> 4;
    const int swzl = (r16 & 7) << 4;

    // XCD-aware bijective block swizzle (2048 % 8 == 0)
    int bid = blockIdx.x;
    int swz = (bid & 7) * 256 + (bid >> 3);
    const int NBN = N_DIM / BN;               // 32
    int bm = swz / NBN;
    int bn = swz % NBN;

    const char* Asrc = (const char*)Apack + (size_t)bm * NT * TILE_BYTES + wv * 4096 + lane * 16;
    const char* Bsrc = (const char*)Wpack + (size_t)bn * NT * TILE_BYTES + wv * 4096 + lane * 16;
    char* Adst = Ash + wv * 4096;
    char* Bdst = Bsh + wv * 4096;

    f32x4 acc[4][4] = {};

#pragma unroll 1
    for (int kt = 0; kt < NT; ++kt) {
        if (kt) __syncthreads();
        const char* ga = Asrc + (size_t)kt * TILE_BYTES;
        const char* gb = Bsrc + (size_t)kt * TILE_BYTES;
#pragma unroll
        for (int j = 0; j < 4; ++j) {
            GLOAD_LDS16(ga + j * 1024, Adst + j * 1024);
            GLOAD_LDS16(gb + j * 1024, Bdst + j * 1024);
        }
        __syncthreads();   // compiler drains vmcnt(0) here

#pragma unroll
        for (int ks = 0; ks < 2; ++ks) {
            half8 af[4], bf[4];
#pragma unroll
            for (int m = 0; m < 4; ++m) {
                int row = wm * 64 + m * 16 + r16;
                af[m] = *(const half8*)(Ash + ((row * 128 + ks * 64 + kq * 16) ^ swzl));
            }
#pragma unroll
            for (int n = 0; n < 4; ++n) {
                int row = wn * 64 + n * 16 + r16;
                bf[n] = *(const half8*)(Bsh + ((row * 128 + ks * 64 + kq * 16) ^ swzl));
            }
#pragma unroll
            for (int m = 0; m < 4; ++m)
#pragma unroll
                for (int n = 0; n < 4; ++n)
                    acc[m][n] = __builtin_amdgcn_mfma_f32_16x16x32_f16(af[m], bf[n], acc[m][n], 0, 0, 0);
        }
    }

    // epilogue: scale + bias, fp32 out
#pragma unroll
    for (int n = 0; n < 4; ++n) {
        int col = bn * BN + wn * 64 + n * 16 + r16;
        float sc = scales[col];
        float bs = bias[col];
#pragma unroll
        for (int m = 0; m < 4; ++m) {
            int row0 = bm * BM + wm * 64 + m * 16 + kq * 4;
#pragma unroll
            for (int j = 0; j < 4; ++j) {
                out[(size_t)(row0 + j) * N_DIM + col] = acc[m][n][j] * sc + bs;
            }
        }
    }
}

// ---------------- round-1 fallback (reg-staged, no workspace needed) ----------------
__global__ __launch_bounds__(256, 2)
void w8a16_gemm(const float* __restrict__ A,
                const void* __restrict__ Wv,
                const float* __restrict__ scales,
                const float* __restrict__ bias,
                float* __restrict__ out) {
    __shared__ char smem[2 * BM * BK * 2];
    char* Ash = smem;
    char* Bsh = smem + BM * BK * 2;

    const int* wprobe = (const int*)Wv;
    bool wi32 = true;
#pragma unroll
    for (int i = 0; i < 16; ++i) {
        int v = wprobe[i];
        wi32 = wi32 && (v >= -128 && v <= 127);
    }

    const int tid  = threadIdx.x;
    const int lane = tid & 63;
    const int wv   = tid >> 6;
    const int wm   = wv >> 1;
    const int wn   = wv & 1;
    const int r16  = lane & 15;
    const int kq   = lane >> 4;
    const int swzl = (r16 & 7) << 4;

    int bid = blockIdx.x;
    int swz = (bid & 7) * 256 + (bid >> 3);
    const int NBN = N_DIM / BN;
    int bm = swz / NBN;
    int bn = swz % NBN;

    const int row_a0 = bm * BM;
    const int row_b0 = bn * BN;

    int cr[4], cc[4];
#pragma unroll
    for (int i = 0; i < 4; ++i) {
        int c = tid + 256 * i;
        cr[i] = c >> 3;
        cc[i] = (c & 7) << 3;
    }

    float4 pa[8];
    int4   pbi[8];
    uint2  pb8[4];

    auto load_tile = [&](int kt) {
        int k0 = kt * BK;
#pragma unroll
        for (int i = 0; i < 4; ++i) {
            const float* p = A + (size_t)(row_a0 + cr[i]) * K_DIM + k0 + cc[i];
            pa[2 * i]     = *(const float4*)p;
            pa[2 * i + 1] = *(const float4*)(p + 4);
        }
        if (wi32) {
            const int* w = (const int*)Wv;
#pragma unroll
            for (int i = 0; i < 4; ++i) {
                const int* p = w + (size_t)(row_b0 + cr[i]) * K_DIM + k0 + cc[i];
                pbi[2 * i]     = *(const int4*)p;
                pbi[2 * i + 1] = *(const int4*)(p + 4);
            }
        } else {
            const signed char* w = (const signed char*)Wv;
#pragma unroll
            for (int i = 0; i < 4; ++i) {
                const signed char* p = w + (size_t)(row_b0 + cr[i]) * K_DIM + k0 + cc[i];
                pb8[i] = *(const uint2*)p;
            }
        }
    };

    auto write_lds = [&]() {
#pragma unroll
        for (int i = 0; i < 4; ++i) {
            int off = (cr[i] * 128 + cc[i] * 2) ^ ((cr[i] & 7) << 4);
            half8 h;
            h[0] = (_Float16)pa[2 * i].x;
            h[1] = (_Float16)pa[2 * i].y;
            h[2] = (_Float16)pa[2 * i].z;
            h[3] = (_Float16)pa[2 * i].w;
            h[4] = (_Float16)pa[2 * i + 1].x;
            h[5] = (_Float16)pa[2 * i + 1].y;
            h[6] = (_Float16)pa[2 * i + 1].z;
            h[7] = (_Float16)pa[2 * i + 1].w;
            *(half8*)(Ash + off) = h;

            half8 g;
            if (wi32) {
                g[0] = (_Float16)pbi[2 * i].x;
                g[1] = (_Float16)pbi[2 * i].y;
                g[2] = (_Float16)pbi[2 * i].z;
                g[3] = (_Float16)pbi[2 * i].w;
                g[4] = (_Float16)pbi[2 * i + 1].x;
                g[5] = (_Float16)pbi[2 * i + 1].y;
                g[6] = (_Float16)pbi[2 * i + 1].z;
                g[7] = (_Float16)pbi[2 * i + 1].w;
            } else {
                unsigned x = pb8[i].x, y = pb8[i].y;
                g[0] = (_Float16)(int)(signed char)(x & 0xff);
                g[1] = (_Float16)(int)(signed char)((x >> 8) & 0xff);
                g[2] = (_Float16)(int)(signed char)((x >> 16) & 0xff);
                g[3] = (_Float16)(int)(signed char)(x >> 24);
                g[4] = (_Float16)(int)(signed char)(y & 0xff);
                g[5] = (_Float16)(int)(signed char)((y >> 8) & 0xff);
                g[6] = (_Float16)(int)(signed char)((y >> 16) & 0xff);
                g[7] = (_Float16)(int)(signed char)(y >> 24);
            }
            *(half8*)(Bsh + off) = g;
        }
    };

    f32x4 acc[4][4] = {};

    auto compute = [&]() {
#pragma unroll
        for (int ks = 0; ks < 2; ++ks) {
            half8 af[4], bf[4];
#pragma unroll
            for (int m = 0; m < 4; ++m) {
                int row = wm * 64 + m * 16 + r16;
                af[m] = *(const half8*)(Ash + ((row * 128 + ks * 64 + kq * 16) ^ swzl));
            }
#pragma unroll
            for (int n = 0; n < 4; ++n) {
                int row = wn * 64 + n * 16 + r16;
                bf[n] = *(const half8*)(Bsh + ((row * 128 + ks * 64 + kq * 16) ^ swzl));
            }
#pragma unroll
            for (int m = 0; m < 4; ++m)
#pragma unroll
                for (int n = 0; n < 4; ++n)
                    acc[m][n] = __builtin_amdgcn_mfma_f32_16x16x32_f16(af[m], bf[n], acc[m][n], 0, 0, 0);
        }
    };

    load_tile(0);
#pragma unroll 1
    for (int kt = 0; kt < NT; ++kt) {
        if (kt) __syncthreads();
        write_lds();
        __syncthreads();
        if (kt + 1 < NT) load_tile(kt + 1);
        compute();
    }

#pragma unroll
    for (int n = 0; n < 4; ++n) {
        int col = row_b0 + wn * 64 + n * 16 + r16;
        float sc = scales[col];
        float bs = bias[col];
#pragma unroll
        for (int m = 0; m < 4; ++m) {
            int row0 = row_a0 + wm * 64 + m * 16 + kq * 4;
#pragma unroll
            for (int j = 0; j < 4; ++j) {
                out[(size_t)(row0 + j) * N_DIM + col] = acc[m][n][j] * sc + bs;
            }
        }
    }
}

extern "C" void kernel_launch(void* const* d_in, const int* in_sizes, int n_in,
                              void* d_out, int out_size, void* d_ws, size_t ws_size,
                              hipStream_t stream) {
    const float* A      = (const float*)d_in[0];
    const void*  W      = d_in[1];
    const float* scales = (const float*)d_in[2];
    const float* bias   = (const float*)d_in[3];
    float*       out    = (float*)d_out;

    const size_t needA = (size_t)M_DIM * K_DIM * 2;   // 64 MiB
    const size_t needW = (size_t)N_DIM * K_DIM * 2;   // 32 MiB

    if (ws_size >= needA + needW) {
        _Float16* Apack = (_Float16*)d_ws;
        _Float16* Wpack = (_Float16*)((char*)d_ws + needA);
        hipLaunchKernelGGL(prep_a, dim3(16384), dim3(256), 0, stream, A, Apack);
        hipLaunchKernelGGL(prep_w, dim3(8192), dim3(256), 0, stream, W, Wpack);
        hipLaunchKernelGGL(w8a16_gemm2, dim3(2048), dim3(256), 0, stream,
                           Apack, Wpack, scales, bias, out);
    } else {
        hipLaunchKernelGGL(w8a16_gemm, dim3(2048), dim3(256), 0, stream,
                           A, W, scales, bias, out);
    }
}

// Round 3
// 307.070 us; speedup vs baseline: 2.1793x; 1.1318x over previous
//
#include <hip/hip_runtime.h>
#include <stdint.h>

typedef _Float16 half8 __attribute__((ext_vector_type(8)));
typedef float f32x4 __attribute__((ext_vector_type(4)));

#define M_DIM 8192
#define N_DIM 4096
#define K_DIM 4096
#define BM 256
#define BN 256
#define BK 64
#define NT (K_DIM / BK)            // 64
#define IMG_BYTES 16384            // one K-half image: 256 rows x 32 cols x 2B
#define KT_BYTES  (2 * IMG_BYTES)  // one K-tile of A or B: 32 KiB

#define GLOAD_LDS16(g, l)                                        \
    __builtin_amdgcn_global_load_lds(                            \
        (const __attribute__((address_space(1))) uint32_t*)(g),  \
        (__attribute__((address_space(3))) uint32_t*)(l), 16, 0, 0)

#define BARRIER()  asm volatile("s_barrier" ::: "memory")
#define WAIT_VM4() asm volatile("s_waitcnt vmcnt(4)" ::: "memory")

// ---------------- prep: A fp32 -> fp16, packed K-half-image tiles ----------------
// layout: tile(bm,kt) at ((bm*NT+kt)*2+ks)*IMG_BYTES; within image: row*64 + kc*2
__global__ __launch_bounds__(256)
void prep_a(const float* __restrict__ A, _Float16* __restrict__ Apack) {
    int g = blockIdx.x * 256 + threadIdx.x;    // 4,194,304 chunks of 8
    int r = g >> 9;                            // row 0..8191
    int c = (g & 511) << 3;                    // col 0..4088 step 8
    const float4* p = (const float4*)(A + (size_t)r * K_DIM + c);
    float4 a0 = p[0], a1 = p[1];
    half8 h;
    h[0] = (_Float16)a0.x; h[1] = (_Float16)a0.y;
    h[2] = (_Float16)a0.z; h[3] = (_Float16)a0.w;
    h[4] = (_Float16)a1.x; h[5] = (_Float16)a1.y;
    h[6] = (_Float16)a1.z; h[7] = (_Float16)a1.w;
    int bm = r >> 8, rl = r & 255;
    int kt = c >> 6, k = c & 63, ks = k >> 5, kc = k & 31;
    size_t off = ((size_t)((bm * NT + kt) * 2 + ks)) * IMG_BYTES + rl * 64 + kc * 2;
    *(half8*)((char*)Apack + off) = h;
}

// ---------------- prep: W int -> fp16, packed K-half-image tiles ----------------
__global__ __launch_bounds__(256)
void prep_w(const void* __restrict__ Wv, _Float16* __restrict__ Wpack) {
    // probe element width: int32 buffer or raw int8?
    const int* wp = (const int*)Wv;
    bool wi32 = true;
#pragma unroll
    for (int i = 0; i < 16; ++i) {
        int v = wp[i];
        wi32 = wi32 && (v >= -128 && v <= 127);
    }
    int g = blockIdx.x * 256 + threadIdx.x;    // 2,097,152 chunks of 8
    int r = g >> 9;                            // row 0..4095
    int c = (g & 511) << 3;
    half8 h;
    if (wi32) {
        const int4* p = (const int4*)((const int*)Wv + (size_t)r * K_DIM + c);
        int4 w0 = p[0], w1 = p[1];
        h[0] = (_Float16)w0.x; h[1] = (_Float16)w0.y;
        h[2] = (_Float16)w0.z; h[3] = (_Float16)w0.w;
        h[4] = (_Float16)w1.x; h[5] = (_Float16)w1.y;
        h[6] = (_Float16)w1.z; h[7] = (_Float16)w1.w;
    } else {
        const signed char* p = (const signed char*)Wv + (size_t)r * K_DIM + c;
        uint2 u = *(const uint2*)p;
        unsigned x = u.x, y = u.y;
        h[0] = (_Float16)(int)(signed char)(x & 0xff);
        h[1] = (_Float16)(int)(signed char)((x >> 8) & 0xff);
        h[2] = (_Float16)(int)(signed char)((x >> 16) & 0xff);
        h[3] = (_Float16)(int)(signed char)(x >> 24);
        h[4] = (_Float16)(int)(signed char)(y & 0xff);
        h[5] = (_Float16)(int)(signed char)((y >> 8) & 0xff);
        h[6] = (_Float16)(int)(signed char)((y >> 16) & 0xff);
        h[7] = (_Float16)(int)(signed char)(y >> 24);
    }
    int bn = r >> 8, rl = r & 255;
    int kt = c >> 6, k = c & 63, ks = k >> 5, kc = k & 31;
    size_t off = ((size_t)((bn * NT + kt) * 2 + ks)) * IMG_BYTES + rl * 64 + kc * 2;
    *(half8*)((char*)Wpack + off) = h;
}

// ---------------- main GEMM: 256x256 tile, 4-phase counted-vmcnt pipeline ----------------
// 8 waves (2M x 4N), 512 threads, 128 KiB LDS (2 K-tile double-buffer).
// Phase p: {ds_read frags; stage prefetch; barrier; setprio(1); 16 MFMA;
//           setprio(0); [counted vmcnt]; barrier}
// vmcnt ledger (per wave, 4 loads per K-half unit):
//   U0(t+1) issued P1 of t, needed P1 of t+1  -> vmcnt(4) before end-P4 barrier
//   U1(t+1) issued P3 of t, needed P3 of t+1  -> vmcnt(4) before end-P2 barrier
// Never drains to 0 in the main loop.
__global__ __launch_bounds__(512, 2)
void w8a16_gemm3(const _Float16* __restrict__ Apack,
                 const _Float16* __restrict__ Wpack,
                 const float* __restrict__ scales,
                 const float* __restrict__ bias,
                 float* __restrict__ out) {
    __shared__ char smem[131072];
    // layout: buf*65536 + (B ? 32768 : 0) + ks*16384 + <image offset>

    const int tid  = threadIdx.x;
    const int lane = tid & 63;
    const int wv   = tid >> 6;     // 0..7
    const int wm   = wv >> 2;      // 0..1  (M half: 128 rows)
    const int wn   = wv & 3;       // 0..3  (N quarter: 64 cols)
    const int r16  = lane & 15;
    const int kq   = lane >> 4;

    // XCD-aware bijective swizzle (512 % 8 == 0)
    int bid = blockIdx.x;
    int swz = (bid & 7) * 64 + (bid >> 3);
    int bm = swz >> 4;             // 0..31
    int bn = swz & 15;             // 0..15

    const char* Abase = (const char*)Apack + (size_t)bm * NT * KT_BYTES + tid * 16;
    const char* Bbase = (const char*)Wpack + (size_t)bn * NT * KT_BYTES + tid * 16;

    auto issueU = [&](int kt_src, int buf, int ks) {
        const char* ga = Abase + (size_t)kt_src * KT_BYTES + ks * IMG_BYTES;
        const char* gb = Bbase + (size_t)kt_src * KT_BYTES + ks * IMG_BYTES;
        char* la = smem + buf * 65536 + ks * IMG_BYTES + tid * 16;
        char* lb = la + 32768;
        GLOAD_LDS16(ga,        la);
        GLOAD_LDS16(ga + 8192, la + 8192);
        GLOAD_LDS16(gb,        lb);
        GLOAD_LDS16(gb + 8192, lb + 8192);
    };

    half8 af[4], bf[4];
    f32x4 acc[8][4] = {};

    auto loadA = [&](int buf, int ks, int mh) {
#pragma unroll
        for (int m = 0; m < 4; ++m) {
            int row = wm * 128 + mh * 64 + m * 16 + r16;
            af[m] = *(const half8*)(smem + buf * 65536 + ks * IMG_BYTES + row * 64 + kq * 16);
        }
    };
    auto loadB = [&](int buf, int ks) {
#pragma unroll
        for (int n = 0; n < 4; ++n) {
            int row = wn * 64 + n * 16 + r16;
            bf[n] = *(const half8*)(smem + buf * 65536 + 32768 + ks * IMG_BYTES + row * 64 + kq * 16);
        }
    };
    // compile-time acc base (rule #20): pass &acc[0] or &acc[4]
    auto mmac4 = [&](f32x4 (*ac)[4]) {
#pragma unroll
        for (int n = 0; n < 4; ++n)
#pragma unroll
            for (int m = 0; m < 4; ++m)
                ac[m][n] = __builtin_amdgcn_mfma_f32_16x16x32_f16(af[m], bf[n], ac[m][n], 0, 0, 0);
    };

    // prologue: stage K-tile 0 into buf0; need U0 landed before P1 reads
    issueU(0, 0, 0);
    issueU(0, 0, 1);
    WAIT_VM4();
    BARRIER();

#pragma unroll 1
    for (int t = 0; t < NT; ++t) {
        int buf  = t & 1;
        int nbuf = buf ^ 1;
        int tn = (t + 1 < NT) ? (t + 1) : t;   // clamped: last iter stages dead data

        // ---- P1: ks=0, m-half 0; issue U0(t+1) ----
        loadA(buf, 0, 0);
        loadB(buf, 0);
        issueU(tn, nbuf, 0);
        BARRIER();
        __builtin_amdgcn_s_setprio(1);
        mmac4(&acc[0]);
        __builtin_amdgcn_s_setprio(0);
        BARRIER();

        // ---- P2: ks=0, m-half 1 (reuse bf) ----
        loadA(buf, 0, 1);
        BARRIER();
        __builtin_amdgcn_s_setprio(1);
        mmac4(&acc[4]);
        __builtin_amdgcn_s_setprio(0);
        WAIT_VM4();          // U1(t) landed (keep U0(t+1) in flight)
        BARRIER();

        // ---- P3: ks=1, m-half 0; issue U1(t+1) ----
        loadA(buf, 1, 0);
        loadB(buf, 1);
        issueU(tn, nbuf, 1);
        BARRIER();
        __builtin_amdgcn_s_setprio(1);
        mmac4(&acc[0]);
        __builtin_amdgcn_s_setprio(0);
        BARRIER();

        // ---- P4: ks=1, m-half 1 (reuse bf) ----
        loadA(buf, 1, 1);
        BARRIER();
        __builtin_amdgcn_s_setprio(1);
        mmac4(&acc[4]);
        __builtin_amdgcn_s_setprio(0);
        WAIT_VM4();          // U0(t+1) landed (keep U1(t+1) in flight)
        BARRIER();
    }

    // ---- epilogue: scale + bias, fp32 out ----
    float sc[4], bs[4];
#pragma unroll
    for (int n = 0; n < 4; ++n) {
        int col = bn * BN + wn * 64 + n * 16 + r16;
        sc[n] = scales[col];
        bs[n] = bias[col];
    }
#pragma unroll
    for (int mi = 0; mi < 8; ++mi) {
        int row0 = bm * BM + wm * 128 + mi * 16 + kq * 4;
#pragma unroll
        for (int n = 0; n < 4; ++n) {
            int col = bn * BN + wn * 64 + n * 16 + r16;
#pragma unroll
            for (int j = 0; j < 4; ++j)
                out[(size_t)(row0 + j) * N_DIM + col] = acc[mi][n][j] * sc[n] + bs[n];
        }
    }
}

// ---------------- fallback (reg-staged, no workspace needed) ----------------
__global__ __launch_bounds__(256, 2)
void w8a16_gemm(const float* __restrict__ A,
                const void* __restrict__ Wv,
                const float* __restrict__ scales,
                const float* __restrict__ bias,
                float* __restrict__ out) {
    __shared__ char smem[2 * 128 * 64 * 2];
    char* Ash = smem;
    char* Bsh = smem + 128 * 64 * 2;

    const int* wprobe = (const int*)Wv;
    bool wi32 = true;
#pragma unroll
    for (int i = 0; i < 16; ++i) {
        int v = wprobe[i];
        wi32 = wi32 && (v >= -128 && v <= 127);
    }

    const int tid  = threadIdx.x;
    const int lane = tid & 63;
    const int wv   = tid >> 6;
    const int wwm  = wv >> 1;
    const int wwn  = wv & 1;
    const int r16  = lane & 15;
    const int kq   = lane >> 4;
    const int swzl = (r16 & 7) << 4;

    int bid = blockIdx.x;
    int swz = (bid & 7) * 256 + (bid >> 3);
    int bm = swz / 32;
    int bn = swz % 32;

    const int row_a0 = bm * 128;
    const int row_b0 = bn * 128;

    int cr[4], cc[4];
#pragma unroll
    for (int i = 0; i < 4; ++i) {
        int c = tid + 256 * i;
        cr[i] = c >> 3;
        cc[i] = (c & 7) << 3;
    }

    float4 pa[8];
    int4   pbi[8];
    uint2  pb8[4];

    auto load_tile = [&](int kt) {
        int k0 = kt * 64;
#pragma unroll
        for (int i = 0; i < 4; ++i) {
            const float* p = A + (size_t)(row_a0 + cr[i]) * K_DIM + k0 + cc[i];
            pa[2 * i]     = *(const float4*)p;
            pa[2 * i + 1] = *(const float4*)(p + 4);
        }
        if (wi32) {
            const int* w = (const int*)Wv;
#pragma unroll
            for (int i = 0; i < 4; ++i) {
                const int* p = w + (size_t)(row_b0 + cr[i]) * K_DIM + k0 + cc[i];
                pbi[2 * i]     = *(const int4*)p;
                pbi[2 * i + 1] = *(const int4*)(p + 4);
            }
        } else {
            const signed char* w = (const signed char*)Wv;
#pragma unroll
            for (int i = 0; i < 4; ++i) {
                const signed char* p = w + (size_t)(row_b0 + cr[i]) * K_DIM + k0 + cc[i];
                pb8[i] = *(const uint2*)p;
            }
        }
    };

    auto write_lds = [&]() {
#pragma unroll
        for (int i = 0; i < 4; ++i) {
            int off = (cr[i] * 128 + cc[i] * 2) ^ ((cr[i] & 7) << 4);
            half8 h;
            h[0] = (_Float16)pa[2 * i].x;
            h[1] = (_Float16)pa[2 * i].y;
            h[2] = (_Float16)pa[2 * i].z;
            h[3] = (_Float16)pa[2 * i].w;
            h[4] = (_Float16)pa[2 * i + 1].x;
            h[5] = (_Float16)pa[2 * i + 1].y;
            h[6] = (_Float16)pa[2 * i + 1].z;
            h[7] = (_Float16)pa[2 * i + 1].w;
            *(half8*)(Ash + off) = h;

            half8 g;
            if (wi32) {
                g[0] = (_Float16)pbi[2 * i].x;
                g[1] = (_Float16)pbi[2 * i].y;
                g[2] = (_Float16)pbi[2 * i].z;
                g[3] = (_Float16)pbi[2 * i].w;
                g[4] = (_Float16)pbi[2 * i + 1].x;
                g[5] = (_Float16)pbi[2 * i + 1].y;
                g[6] = (_Float16)pbi[2 * i + 1].z;
                g[7] = (_Float16)pbi[2 * i + 1].w;
            } else {
                unsigned x = pb8[i].x, y = pb8[i].y;
                g[0] = (_Float16)(int)(signed char)(x & 0xff);
                g[1] = (_Float16)(int)(signed char)((x >> 8) & 0xff);
                g[2] = (_Float16)(int)(signed char)((x >> 16) & 0xff);
                g[3] = (_Float16)(int)(signed char)(x >> 24);
                g[4] = (_Float16)(int)(signed char)(y & 0xff);
                g[5] = (_Float16)(int)(signed char)((y >> 8) & 0xff);
                g[6] = (_Float16)(int)(signed char)((y >> 16) & 0xff);
                g[7] = (_Float16)(int)(signed char)(y >> 24);
            }
            *(half8*)(Bsh + off) = g;
        }
    };

    f32x4 acc[4][4] = {};

    auto compute = [&]() {
#pragma unroll
        for (int ks = 0; ks < 2; ++ks) {
            half8 af[4], bfr[4];
#pragma unroll
            for (int m = 0; m < 4; ++m) {
                int row = wwm * 64 + m * 16 + r16;
                af[m] = *(const half8*)(Ash + ((row * 128 + ks * 64 + kq * 16) ^ swzl));
            }
#pragma unroll
            for (int n = 0; n < 4; ++n) {
                int row = wwn * 64 + n * 16 + r16;
                bfr[n] = *(const half8*)(Bsh + ((row * 128 + ks * 64 + kq * 16) ^ swzl));
            }
#pragma unroll
            for (int m = 0; m < 4; ++m)
#pragma unroll
                for (int n = 0; n < 4; ++n)
                    acc[m][n] = __builtin_amdgcn_mfma_f32_16x16x32_f16(af[m], bfr[n], acc[m][n], 0, 0, 0);
        }
    };

    load_tile(0);
#pragma unroll 1
    for (int kt = 0; kt < NT; ++kt) {
        if (kt) __syncthreads();
        write_lds();
        __syncthreads();
        if (kt + 1 < NT) load_tile(kt + 1);
        compute();
    }

#pragma unroll
    for (int n = 0; n < 4; ++n) {
        int col = row_b0 + wwn * 64 + n * 16 + r16;
        float s = scales[col];
        float b = bias[col];
#pragma unroll
        for (int m = 0; m < 4; ++m) {
            int row0 = row_a0 + wwm * 64 + m * 16 + kq * 4;
#pragma unroll
            for (int j = 0; j < 4; ++j) {
                out[(size_t)(row0 + j) * N_DIM + col] = acc[m][n][j] * s + b;
            }
        }
    }
}

extern "C" void kernel_launch(void* const* d_in, const int* in_sizes, int n_in,
                              void* d_out, int out_size, void* d_ws, size_t ws_size,
                              hipStream_t stream) {
    const float* A      = (const float*)d_in[0];
    const void*  W      = d_in[1];
    const float* scales = (const float*)d_in[2];
    const float* bias   = (const float*)d_in[3];
    float*       out    = (float*)d_out;

    const size_t needA = (size_t)M_DIM * K_DIM * 2;   // 64 MiB
    const size_t needW = (size_t)N_DIM * K_DIM * 2;   // 32 MiB

    if (ws_size >= needA + needW) {
        _Float16* Apack = (_Float16*)d_ws;
        _Float16* Wpack = (_Float16*)((char*)d_ws + needA);
        hipLaunchKernelGGL(prep_a, dim3(16384), dim3(256), 0, stream, A, Apack);
        hipLaunchKernelGGL(prep_w, dim3(8192), dim3(256), 0, stream, W, Wpack);
        hipLaunchKernelGGL(w8a16_gemm3, dim3(512), dim3(512), 0, stream,
                           Apack, Wpack, scales, bias, out);
    } else {
        hipLaunchKernelGGL(w8a16_gemm, dim3(2048), dim3(256), 0, stream,
                           A, W, scales, bias, out);
    }
}

// Round 4
// 297.951 us; speedup vs baseline: 2.2460x; 1.0306x over previous
//
#include <hip/hip_runtime.h>
#include <stdint.h>

typedef _Float16 half8 __attribute__((ext_vector_type(8)));
typedef float f32x4 __attribute__((ext_vector_type(4)));

#define M_DIM 8192
#define N_DIM 4096
#define K_DIM 4096
#define BM 256
#define BN 256
#define BK 64
#define NT (K_DIM / BK)            // 64
#define IMG_BYTES 16384            // one K-half image: 256 rows x 32 cols x 2B
#define KT_BYTES  (2 * IMG_BYTES)  // one K-tile of A or B: 32 KiB

#define GLOAD_LDS16(g, l)                                        \
    __builtin_amdgcn_global_load_lds(                            \
        (const __attribute__((address_space(1))) uint32_t*)(g),  \
        (__attribute__((address_space(3))) uint32_t*)(l), 16, 0, 0)

#define BARRIER()  asm volatile("s_barrier" ::: "memory")
#define WAIT_VM4() asm volatile("s_waitcnt vmcnt(4)" ::: "memory")

// In-image byte offset for (row, 16B-slot), with bank-conflict swizzle:
// slot' = slot ^ (row>>1 & 3). Row stride 64B puts bank-quad = {row&1, slot};
// XOR-ing row bits [2:1] into the slot spreads each kq-group's 16 rows over
// all 8 bank quads -> uniform 2 addr/bank per wave ds_read_b128 (conflict-free).
// Involution applied on BOTH pack-write and LDS-read; global_load_lds stays linear.
__device__ __forceinline__ int img_off(int row, int slot) {
    return row * 64 + ((slot ^ ((row >> 1) & 3)) << 4);
}

// ---------------- prep: A fp32 -> fp16, packed K-half-image tiles ----------------
// tile(bm,kt) at ((bm*NT+kt)*2+ks)*IMG_BYTES; within image: img_off(row, kc/8)
__global__ __launch_bounds__(256)
void prep_a(const float* __restrict__ A, _Float16* __restrict__ Apack) {
    int g = blockIdx.x * 256 + threadIdx.x;    // 4,194,304 chunks of 8
    int r = g >> 9;                            // row 0..8191
    int c = (g & 511) << 3;                    // col 0..4088 step 8
    const float4* p = (const float4*)(A + (size_t)r * K_DIM + c);
    float4 a0 = p[0], a1 = p[1];
    half8 h;
    h[0] = (_Float16)a0.x; h[1] = (_Float16)a0.y;
    h[2] = (_Float16)a0.z; h[3] = (_Float16)a0.w;
    h[4] = (_Float16)a1.x; h[5] = (_Float16)a1.y;
    h[6] = (_Float16)a1.z; h[7] = (_Float16)a1.w;
    int bm = r >> 8, rl = r & 255;
    int kt = c >> 6, k = c & 63, ks = k >> 5, kc = k & 31;
    size_t off = ((size_t)((bm * NT + kt) * 2 + ks)) * IMG_BYTES + img_off(rl, kc >> 3);
    *(half8*)((char*)Apack + off) = h;
}

// ---------------- prep: W int -> fp16, packed K-half-image tiles ----------------
__global__ __launch_bounds__(256)
void prep_w(const void* __restrict__ Wv, _Float16* __restrict__ Wpack) {
    // probe element width: int32 buffer or raw int8?
    const int* wp = (const int*)Wv;
    bool wi32 = true;
#pragma unroll
    for (int i = 0; i < 16; ++i) {
        int v = wp[i];
        wi32 = wi32 && (v >= -128 && v <= 127);
    }
    int g = blockIdx.x * 256 + threadIdx.x;    // 2,097,152 chunks of 8
    int r = g >> 9;                            // row 0..4095
    int c = (g & 511) << 3;
    half8 h;
    if (wi32) {
        const int4* p = (const int4*)((const int*)Wv + (size_t)r * K_DIM + c);
        int4 w0 = p[0], w1 = p[1];
        h[0] = (_Float16)w0.x; h[1] = (_Float16)w0.y;
        h[2] = (_Float16)w0.z; h[3] = (_Float16)w0.w;
        h[4] = (_Float16)w1.x; h[5] = (_Float16)w1.y;
        h[6] = (_Float16)w1.z; h[7] = (_Float16)w1.w;
    } else {
        const signed char* p = (const signed char*)Wv + (size_t)r * K_DIM + c;
        uint2 u = *(const uint2*)p;
        unsigned x = u.x, y = u.y;
        h[0] = (_Float16)(int)(signed char)(x & 0xff);
        h[1] = (_Float16)(int)(signed char)((x >> 8) & 0xff);
        h[2] = (_Float16)(int)(signed char)((x >> 16) & 0xff);
        h[3] = (_Float16)(int)(signed char)(x >> 24);
        h[4] = (_Float16)(int)(signed char)(y & 0xff);
        h[5] = (_Float16)(int)(signed char)((y >> 8) & 0xff);
        h[6] = (_Float16)(int)(signed char)((y >> 16) & 0xff);
        h[7] = (_Float16)(int)(signed char)(y >> 24);
    }
    int bn = r >> 8, rl = r & 255;
    int kt = c >> 6, k = c & 63, ks = k >> 5, kc = k & 31;
    size_t off = ((size_t)((bn * NT + kt) * 2 + ks)) * IMG_BYTES + img_off(rl, kc >> 3);
    *(half8*)((char*)Wpack + off) = h;
}

// ---------------- main GEMM: 256x256 tile, 4-phase counted-vmcnt pipeline ----------------
// 8 waves (2M x 4N), 512 threads, 128 KiB LDS (2 K-tile double-buffer).
// vmcnt ledger (per wave, 4 loads per K-half unit):
//   U0(t+1) issued P1 of t, needed P1 of t+1  -> vmcnt(4) before end-P4 barrier
//   U1(t+1) issued P3 of t, needed P3 of t+1  -> vmcnt(4) before end-P2 barrier
// Never drains to 0 in the main loop.
__global__ __launch_bounds__(512, 2)
void w8a16_gemm3(const _Float16* __restrict__ Apack,
                 const _Float16* __restrict__ Wpack,
                 const float* __restrict__ scales,
                 const float* __restrict__ bias,
                 float* __restrict__ out) {
    __shared__ char smem[131072];
    // layout: buf*65536 + (B ? 32768 : 0) + ks*16384 + <image offset>

    const int tid  = threadIdx.x;
    const int lane = tid & 63;
    const int wv   = tid >> 6;     // 0..7
    const int wm   = wv >> 2;      // 0..1  (M half: 128 rows)
    const int wn   = wv & 3;       // 0..3  (N quarter: 64 cols)
    const int r16  = lane & 15;
    const int kq   = lane >> 4;

    // XCD-aware bijective swizzle (512 % 8 == 0)
    int bid = blockIdx.x;
    int swz = (bid & 7) * 64 + (bid >> 3);
    int bm = swz >> 4;             // 0..31
    int bn = swz & 15;             // 0..15

    const char* Abase = (const char*)Apack + (size_t)bm * NT * KT_BYTES + tid * 16;
    const char* Bbase = (const char*)Wpack + (size_t)bn * NT * KT_BYTES + tid * 16;

    auto issueU = [&](int kt_src, int buf, int ks) {
        const char* ga = Abase + (size_t)kt_src * KT_BYTES + ks * IMG_BYTES;
        const char* gb = Bbase + (size_t)kt_src * KT_BYTES + ks * IMG_BYTES;
        char* la = smem + buf * 65536 + ks * IMG_BYTES + tid * 16;
        char* lb = la + 32768;
        GLOAD_LDS16(ga,        la);
        GLOAD_LDS16(ga + 8192, la + 8192);
        GLOAD_LDS16(gb,        lb);
        GLOAD_LDS16(gb + 8192, lb + 8192);
    };

    half8 af[4], bf[4];
    f32x4 acc[8][4] = {};

    auto loadA = [&](int buf, int ks, int mh) {
#pragma unroll
        for (int m = 0; m < 4; ++m) {
            int row = wm * 128 + mh * 64 + m * 16 + r16;
            af[m] = *(const half8*)(smem + buf * 65536 + ks * IMG_BYTES + img_off(row, kq));
        }
    };
    auto loadB = [&](int buf, int ks) {
#pragma unroll
        for (int n = 0; n < 4; ++n) {
            int row = wn * 64 + n * 16 + r16;
            bf[n] = *(const half8*)(smem + buf * 65536 + 32768 + ks * IMG_BYTES + img_off(row, kq));
        }
    };
    // compile-time acc base (rule #20): pass &acc[0] or &acc[4]
    auto mmac4 = [&](f32x4 (*ac)[4]) {
#pragma unroll
        for (int n = 0; n < 4; ++n)
#pragma unroll
            for (int m = 0; m < 4; ++m)
                ac[m][n] = __builtin_amdgcn_mfma_f32_16x16x32_f16(af[m], bf[n], ac[m][n], 0, 0, 0);
    };

    // prologue: stage K-tile 0 into buf0; need ks=0 landed before P1 reads
    issueU(0, 0, 0);
    issueU(0, 0, 1);
    WAIT_VM4();
    BARRIER();

#pragma unroll 1
    for (int t = 0; t < NT; ++t) {
        int buf  = t & 1;
        int nbuf = buf ^ 1;
        int tn = (t + 1 < NT) ? (t + 1) : t;   // clamped: last iter stages dead data

        // ---- P1: ks=0, m-half 0; issue U0(t+1) ----
        loadA(buf, 0, 0);
        loadB(buf, 0);
        issueU(tn, nbuf, 0);
        BARRIER();
        __builtin_amdgcn_s_setprio(1);
        mmac4(&acc[0]);
        __builtin_amdgcn_s_setprio(0);
        BARRIER();

        // ---- P2: ks=0, m-half 1 (reuse bf) ----
        loadA(buf, 0, 1);
        BARRIER();
        __builtin_amdgcn_s_setprio(1);
        mmac4(&acc[4]);
        __builtin_amdgcn_s_setprio(0);
        WAIT_VM4();          // U1(t) landed (keep U0(t+1) in flight)
        BARRIER();

        // ---- P3: ks=1, m-half 0; issue U1(t+1) ----
        loadA(buf, 1, 0);
        loadB(buf, 1);
        issueU(tn, nbuf, 1);
        BARRIER();
        __builtin_amdgcn_s_setprio(1);
        mmac4(&acc[0]);
        __builtin_amdgcn_s_setprio(0);
        BARRIER();

        // ---- P4: ks=1, m-half 1 (reuse bf) ----
        loadA(buf, 1, 1);
        BARRIER();
        __builtin_amdgcn_s_setprio(1);
        mmac4(&acc[4]);
        __builtin_amdgcn_s_setprio(0);
        WAIT_VM4();          // U0(t+1) landed (keep U1(t+1) in flight)
        BARRIER();
    }

    // ---- epilogue: scale + bias, fp32 out ----
    float sc[4], bs[4];
#pragma unroll
    for (int n = 0; n < 4; ++n) {
        int col = bn * BN + wn * 64 + n * 16 + r16;
        sc[n] = scales[col];
        bs[n] = bias[col];
    }
#pragma unroll
    for (int mi = 0; mi < 8; ++mi) {
        int row0 = bm * BM + wm * 128 + mi * 16 + kq * 4;
#pragma unroll
        for (int n = 0; n < 4; ++n) {
            int col = bn * BN + wn * 64 + n * 16 + r16;
#pragma unroll
            for (int j = 0; j < 4; ++j)
                out[(size_t)(row0 + j) * N_DIM + col] = acc[mi][n][j] * sc[n] + bs[n];
        }
    }
}

// ---------------- fallback (reg-staged, no workspace needed) ----------------
__global__ __launch_bounds__(256, 2)
void w8a16_gemm(const float* __restrict__ A,
                const void* __restrict__ Wv,
                const float* __restrict__ scales,
                const float* __restrict__ bias,
                float* __restrict__ out) {
    __shared__ char smem[2 * 128 * 64 * 2];
    char* Ash = smem;
    char* Bsh = smem + 128 * 64 * 2;

    const int* wprobe = (const int*)Wv;
    bool wi32 = true;
#pragma unroll
    for (int i = 0; i < 16; ++i) {
        int v = wprobe[i];
        wi32 = wi32 && (v >= -128 && v <= 127);
    }

    const int tid  = threadIdx.x;
    const int lane = tid & 63;
    const int wv   = tid >> 6;
    const int wwm  = wv >> 1;
    const int wwn  = wv & 1;
    const int r16  = lane & 15;
    const int kq   = lane >> 4;
    const int swzl = (r16 & 7) << 4;

    int bid = blockIdx.x;
    int swz = (bid & 7) * 256 + (bid >> 3);
    int bm = swz / 32;
    int bn = swz % 32;

    const int row_a0 = bm * 128;
    const int row_b0 = bn * 128;

    int cr[4], cc[4];
#pragma unroll
    for (int i = 0; i < 4; ++i) {
        int c = tid + 256 * i;
        cr[i] = c >> 3;
        cc[i] = (c & 7) << 3;
    }

    float4 pa[8];
    int4   pbi[8];
    uint2  pb8[4];

    auto load_tile = [&](int kt) {
        int k0 = kt * 64;
#pragma unroll
        for (int i = 0; i < 4; ++i) {
            const float* p = A + (size_t)(row_a0 + cr[i]) * K_DIM + k0 + cc[i];
            pa[2 * i]     = *(const float4*)p;
            pa[2 * i + 1] = *(const float4*)(p + 4);
        }
        if (wi32) {
            const int* w = (const int*)Wv;
#pragma unroll
            for (int i = 0; i < 4; ++i) {
                const int* p = w + (size_t)(row_b0 + cr[i]) * K_DIM + k0 + cc[i];
                pbi[2 * i]     = *(const int4*)p;
                pbi[2 * i + 1] = *(const int4*)(p + 4);
            }
        } else {
            const signed char* w = (const signed char*)Wv;
#pragma unroll
            for (int i = 0; i < 4; ++i) {
                const signed char* p = w + (size_t)(row_b0 + cr[i]) * K_DIM + k0 + cc[i];
                pb8[i] = *(const uint2*)p;
            }
        }
    };

    auto write_lds = [&]() {
#pragma unroll
        for (int i = 0; i < 4; ++i) {
            int off = (cr[i] * 128 + cc[i] * 2) ^ ((cr[i] & 7) << 4);
            half8 h;
            h[0] = (_Float16)pa[2 * i].x;
            h[1] = (_Float16)pa[2 * i].y;
            h[2] = (_Float16)pa[2 * i].z;
            h[3] = (_Float16)pa[2 * i].w;
            h[4] = (_Float16)pa[2 * i + 1].x;
            h[5] = (_Float16)pa[2 * i + 1].y;
            h[6] = (_Float16)pa[2 * i + 1].z;
            h[7] = (_Float16)pa[2 * i + 1].w;
            *(half8*)(Ash + off) = h;

            half8 g;
            if (wi32) {
                g[0] = (_Float16)pbi[2 * i].x;
                g[1] = (_Float16)pbi[2 * i].y;
                g[2] = (_Float16)pbi[2 * i].z;
                g[3] = (_Float16)pbi[2 * i].w;
                g[4] = (_Float16)pbi[2 * i + 1].x;
                g[5] = (_Float16)pbi[2 * i + 1].y;
                g[6] = (_Float16)pbi[2 * i + 1].z;
                g[7] = (_Float16)pbi[2 * i + 1].w;
            } else {
                unsigned x = pb8[i].x, y = pb8[i].y;
                g[0] = (_Float16)(int)(signed char)(x & 0xff);
                g[1] = (_Float16)(int)(signed char)((x >> 8) & 0xff);
                g[2] = (_Float16)(int)(signed char)((x >> 16) & 0xff);
                g[3] = (_Float16)(int)(signed char)(x >> 24);
                g[4] = (_Float16)(int)(signed char)(y & 0xff);
                g[5] = (_Float16)(int)(signed char)((y >> 8) & 0xff);
                g[6] = (_Float16)(int)(signed char)((y >> 16) & 0xff);
                g[7] = (_Float16)(int)(signed char)(y >> 24);
            }
            *(half8*)(Bsh + off) = g;
        }
    };

    f32x4 acc[4][4] = {};

    auto compute = [&]() {
#pragma unroll
        for (int ks = 0; ks < 2; ++ks) {
            half8 af[4], bfr[4];
#pragma unroll
            for (int m = 0; m < 4; ++m) {
                int row = wwm * 64 + m * 16 + r16;
                af[m] = *(const half8*)(Ash + ((row * 128 + ks * 64 + kq * 16) ^ swzl));
            }
#pragma unroll
            for (int n = 0; n < 4; ++n) {
                int row = wwn * 64 + n * 16 + r16;
                bfr[n] = *(const half8*)(Bsh + ((row * 128 + ks * 64 + kq * 16) ^ swzl));
            }
#pragma unroll
            for (int m = 0; m < 4; ++m)
#pragma unroll
                for (int n = 0; n < 4; ++n)
                    acc[m][n] = __builtin_amdgcn_mfma_f32_16x16x32_f16(af[m], bfr[n], acc[m][n], 0, 0, 0);
        }
    };

    load_tile(0);
#pragma unroll 1
    for (int kt = 0; kt < NT; ++kt) {
        if (kt) __syncthreads();
        write_lds();
        __syncthreads();
        if (kt + 1 < NT) load_tile(kt + 1);
        compute();
    }

#pragma unroll
    for (int n = 0; n < 4; ++n) {
        int col = row_b0 + wwn * 64 + n * 16 + r16;
        float s = scales[col];
        float b = bias[col];
#pragma unroll
        for (int m = 0; m < 4; ++m) {
            int row0 = row_a0 + wwm * 64 + m * 16 + kq * 4;
#pragma unroll
            for (int j = 0; j < 4; ++j) {
                out[(size_t)(row0 + j) * N_DIM + col] = acc[m][n][j] * s + b;
            }
        }
    }
}

extern "C" void kernel_launch(void* const* d_in, const int* in_sizes, int n_in,
                              void* d_out, int out_size, void* d_ws, size_t ws_size,
                              hipStream_t stream) {
    const float* A      = (const float*)d_in[0];
    const void*  W      = d_in[1];
    const float* scales = (const float*)d_in[2];
    const float* bias   = (const float*)d_in[3];
    float*       out    = (float*)d_out;

    const size_t needA = (size_t)M_DIM * K_DIM * 2;   // 64 MiB
    const size_t needW = (size_t)N_DIM * K_DIM * 2;   // 32 MiB

    if (ws_size >= needA + needW) {
        _Float16* Apack = (_Float16*)d_ws;
        _Float16* Wpack = (_Float16*)((char*)d_ws + needA);
        hipLaunchKernelGGL(prep_a, dim3(16384), dim3(256), 0, stream, A, Apack);
        hipLaunchKernelGGL(prep_w, dim3(8192), dim3(256), 0, stream, W, Wpack);
        hipLaunchKernelGGL(w8a16_gemm3, dim3(512), dim3(512), 0, stream,
                           Apack, Wpack, scales, bias, out);
    } else {
        hipLaunchKernelGGL(w8a16_gemm, dim3(2048), dim3(256), 0, stream,
                           A, W, scales, bias, out);
    }
}

// Round 5
// 295.527 us; speedup vs baseline: 2.2644x; 1.0082x over previous
//
#include <hip/hip_runtime.h>
#include <stdint.h>

typedef _Float16 half8 __attribute__((ext_vector_type(8)));
typedef float f32x4 __attribute__((ext_vector_type(4)));

#define M_DIM 8192
#define N_DIM 4096
#define K_DIM 4096
#define BM 256
#define BN 256
#define BK 64
#define NT (K_DIM / BK)            // 64
#define IMG_BYTES 16384            // one K-half image: 256 rows x 32 cols x 2B
#define KT_BYTES  (2 * IMG_BYTES)  // one K-tile of A or B: 32 KiB

#define GLOAD_LDS16(g, l)                                        \
    __builtin_amdgcn_global_load_lds(                            \
        (const __attribute__((address_space(1))) uint32_t*)(g),  \
        (__attribute__((address_space(3))) uint32_t*)(l), 16, 0, 0)

#define BARRIER()  asm volatile("s_barrier" ::: "memory")
#define WAIT_VM0() asm volatile("s_waitcnt vmcnt(0)" ::: "memory")

// In-image byte offset for (row, 16B-slot), with bank-conflict swizzle:
// slot' = slot ^ (row>>1 & 3). Applied on BOTH pack-write and LDS-read;
// global_load_lds stays byte-linear (rule #21).
__device__ __forceinline__ int img_off(int row, int slot) {
    return row * 64 + ((slot ^ ((row >> 1) & 3)) << 4);
}

// ---------------- prep: A fp32 -> fp16, packed K-half-image tiles ----------------
// tile(bm,kt) at ((bm*NT+kt)*2+ks)*IMG_BYTES; within image: img_off(row, kc/8)
__global__ __launch_bounds__(256)
void prep_a(const float* __restrict__ A, _Float16* __restrict__ Apack) {
    int g = blockIdx.x * 256 + threadIdx.x;    // 4,194,304 chunks of 8
    int r = g >> 9;                            // row 0..8191
    int c = (g & 511) << 3;                    // col 0..4088 step 8
    const float4* p = (const float4*)(A + (size_t)r * K_DIM + c);
    float4 a0 = p[0], a1 = p[1];
    half8 h;
    h[0] = (_Float16)a0.x; h[1] = (_Float16)a0.y;
    h[2] = (_Float16)a0.z; h[3] = (_Float16)a0.w;
    h[4] = (_Float16)a1.x; h[5] = (_Float16)a1.y;
    h[6] = (_Float16)a1.z; h[7] = (_Float16)a1.w;
    int bm = r >> 8, rl = r & 255;
    int kt = c >> 6, k = c & 63, ks = k >> 5, kc = k & 31;
    size_t off = ((size_t)((bm * NT + kt) * 2 + ks)) * IMG_BYTES + img_off(rl, kc >> 3);
    *(half8*)((char*)Apack + off) = h;
}

// ---------------- prep: W int -> fp16, packed K-half-image tiles ----------------
__global__ __launch_bounds__(256)
void prep_w(const void* __restrict__ Wv, _Float16* __restrict__ Wpack) {
    // probe element width: int32 buffer or raw int8?
    const int* wp = (const int*)Wv;
    bool wi32 = true;
#pragma unroll
    for (int i = 0; i < 16; ++i) {
        int v = wp[i];
        wi32 = wi32 && (v >= -128 && v <= 127);
    }
    int g = blockIdx.x * 256 + threadIdx.x;    // 2,097,152 chunks of 8
    int r = g >> 9;                            // row 0..4095
    int c = (g & 511) << 3;
    half8 h;
    if (wi32) {
        const int4* p = (const int4*)((const int*)Wv + (size_t)r * K_DIM + c);
        int4 w0 = p[0], w1 = p[1];
        h[0] = (_Float16)w0.x; h[1] = (_Float16)w0.y;
        h[2] = (_Float16)w0.z; h[3] = (_Float16)w0.w;
        h[4] = (_Float16)w1.x; h[5] = (_Float16)w1.y;
        h[6] = (_Float16)w1.z; h[7] = (_Float16)w1.w;
    } else {
        const signed char* p = (const signed char*)Wv + (size_t)r * K_DIM + c;
        uint2 u = *(const uint2*)p;
        unsigned x = u.x, y = u.y;
        h[0] = (_Float16)(int)(signed char)(x & 0xff);
        h[1] = (_Float16)(int)(signed char)((x >> 8) & 0xff);
        h[2] = (_Float16)(int)(signed char)((x >> 16) & 0xff);
        h[3] = (_Float16)(int)(signed char)(x >> 24);
        h[4] = (_Float16)(int)(signed char)(y & 0xff);
        h[5] = (_Float16)(int)(signed char)((y >> 8) & 0xff);
        h[6] = (_Float16)(int)(signed char)((y >> 16) & 0xff);
        h[7] = (_Float16)(int)(signed char)(y >> 24);
    }
    int bn = r >> 8, rl = r & 255;
    int kt = c >> 6, k = c & 63, ks = k >> 5, kc = k & 31;
    size_t off = ((size_t)((bn * NT + kt) * 2 + ks)) * IMG_BYTES + img_off(rl, kc >> 3);
    *(half8*)((char*)Wpack + off) = h;
}

// ---------------- main GEMM: 256x256 tile, 1-barrier-per-K-tile pipeline ----------------
// 8 waves (2M x 4N), 512 threads, 128 KiB LDS (2 K-tile double-buffer).
// Schedule per K-tile t (buf = t&1, nbuf = buf^1):
//   [top: barrier from prev iter guarantees buf fully staged & visible]
//   issue 8 global_load_lds for tile t+1 -> nbuf   (prefetch dist = full tile)
//   straight-line compute: 24 ds_read_b128 + 64 MFMA on buf, NO barriers
//     (waves de-lockstep; one wave's LDS reads hide under another's MFMAs)
//   vmcnt(0)   <- own t+1 loads had ~full compute block to land: free drain
//   s_barrier  <- all waves' loads visible; all reads of buf done
// Hazards: stage(t+1 -> nbuf) vs reads of nbuf(t-1): closed by prev barrier.
//          reads of nbuf(t+1) vs stage landing: closed by vmcnt(0)+barrier.
__global__ __launch_bounds__(512, 2)
void w8a16_gemm3(const _Float16* __restrict__ Apack,
                 const _Float16* __restrict__ Wpack,
                 const float* __restrict__ scales,
                 const float* __restrict__ bias,
                 float* __restrict__ out) {
    __shared__ char smem[131072];
    // layout: buf*65536 + (B ? 32768 : 0) + ks*16384 + <image offset>

    const int tid  = threadIdx.x;
    const int lane = tid & 63;
    const int wv   = tid >> 6;     // 0..7
    const int wm   = wv >> 2;      // 0..1  (M half: 128 rows)
    const int wn   = wv & 3;       // 0..3  (N quarter: 64 cols)
    const int r16  = lane & 15;
    const int kq   = lane >> 4;

    // XCD-aware bijective swizzle (512 % 8 == 0)
    int bid = blockIdx.x;
    int swz = (bid & 7) * 64 + (bid >> 3);
    int bm = swz >> 4;             // 0..31
    int bn = swz & 15;             // 0..15

    const char* Abase = (const char*)Apack + (size_t)bm * NT * KT_BYTES + tid * 16;
    const char* Bbase = (const char*)Wpack + (size_t)bn * NT * KT_BYTES + tid * 16;

    auto issueU = [&](int kt_src, int buf, int ks) {
        const char* ga = Abase + (size_t)kt_src * KT_BYTES + ks * IMG_BYTES;
        const char* gb = Bbase + (size_t)kt_src * KT_BYTES + ks * IMG_BYTES;
        char* la = smem + buf * 65536 + ks * IMG_BYTES + tid * 16;
        char* lb = la + 32768;
        GLOAD_LDS16(ga,        la);
        GLOAD_LDS16(ga + 8192, la + 8192);
        GLOAD_LDS16(gb,        lb);
        GLOAD_LDS16(gb + 8192, lb + 8192);
    };

    half8 af[4], bf[4];
    f32x4 acc[8][4] = {};

    auto loadA = [&](int buf, int ks, int mh) {
#pragma unroll
        for (int m = 0; m < 4; ++m) {
            int row = wm * 128 + mh * 64 + m * 16 + r16;
            af[m] = *(const half8*)(smem + buf * 65536 + ks * IMG_BYTES + img_off(row, kq));
        }
    };
    auto loadB = [&](int buf, int ks) {
#pragma unroll
        for (int n = 0; n < 4; ++n) {
            int row = wn * 64 + n * 16 + r16;
            bf[n] = *(const half8*)(smem + buf * 65536 + 32768 + ks * IMG_BYTES + img_off(row, kq));
        }
    };
    // compile-time acc base (rule #20): pass &acc[0] or &acc[4]
    auto mmac4 = [&](f32x4 (*ac)[4]) {
#pragma unroll
        for (int n = 0; n < 4; ++n)
#pragma unroll
            for (int m = 0; m < 4; ++m)
                ac[m][n] = __builtin_amdgcn_mfma_f32_16x16x32_f16(af[m], bf[n], ac[m][n], 0, 0, 0);
    };

    // prologue: stage K-tile 0 into buf0
    issueU(0, 0, 0);
    issueU(0, 0, 1);
    WAIT_VM0();
    BARRIER();

#pragma unroll 1
    for (int t = 0; t < NT; ++t) {
        int buf  = t & 1;
        int nbuf = buf ^ 1;

        // prefetch next tile first: max issue->wait distance
        if (t + 1 < NT) {
            issueU(t + 1, nbuf, 0);
            issueU(t + 1, nbuf, 1);
        }

        // straight-line compute on buf: no intra-tile barriers
        loadA(buf, 0, 0);
        loadB(buf, 0);
        __builtin_amdgcn_s_setprio(1);
        mmac4(&acc[0]);
        __builtin_amdgcn_s_setprio(0);

        loadA(buf, 0, 1);
        __builtin_amdgcn_s_setprio(1);
        mmac4(&acc[4]);
        __builtin_amdgcn_s_setprio(0);

        loadA(buf, 1, 0);
        loadB(buf, 1);
        __builtin_amdgcn_s_setprio(1);
        mmac4(&acc[0]);
        __builtin_amdgcn_s_setprio(0);

        loadA(buf, 1, 1);
        __builtin_amdgcn_s_setprio(1);
        mmac4(&acc[4]);
        __builtin_amdgcn_s_setprio(0);

        WAIT_VM0();   // own t+1 stage loads landed (had full compute to cover)
        BARRIER();    // all waves' loads visible; all buf reads done
    }

    // ---- epilogue: scale + bias, fp32 out ----
    float sc[4], bs[4];
#pragma unroll
    for (int n = 0; n < 4; ++n) {
        int col = bn * BN + wn * 64 + n * 16 + r16;
        sc[n] = scales[col];
        bs[n] = bias[col];
    }
#pragma unroll
    for (int mi = 0; mi < 8; ++mi) {
        int row0 = bm * BM + wm * 128 + mi * 16 + kq * 4;
#pragma unroll
        for (int n = 0; n < 4; ++n) {
            int col = bn * BN + wn * 64 + n * 16 + r16;
#pragma unroll
            for (int j = 0; j < 4; ++j)
                out[(size_t)(row0 + j) * N_DIM + col] = acc[mi][n][j] * sc[n] + bs[n];
        }
    }
}

// ---------------- fallback (reg-staged, no workspace needed) ----------------
__global__ __launch_bounds__(256, 2)
void w8a16_gemm(const float* __restrict__ A,
                const void* __restrict__ Wv,
                const float* __restrict__ scales,
                const float* __restrict__ bias,
                float* __restrict__ out) {
    __shared__ char smem[2 * 128 * 64 * 2];
    char* Ash = smem;
    char* Bsh = smem + 128 * 64 * 2;

    const int* wprobe = (const int*)Wv;
    bool wi32 = true;
#pragma unroll
    for (int i = 0; i < 16; ++i) {
        int v = wprobe[i];
        wi32 = wi32 && (v >= -128 && v <= 127);
    }

    const int tid  = threadIdx.x;
    const int lane = tid & 63;
    const int wv   = tid >> 6;
    const int wwm  = wv >> 1;
    const int wwn  = wv & 1;
    const int r16  = lane & 15;
    const int kq   = lane >> 4;
    const int swzl = (r16 & 7) << 4;

    int bid = blockIdx.x;
    int swz = (bid & 7) * 256 + (bid >> 3);
    int bm = swz / 32;
    int bn = swz % 32;

    const int row_a0 = bm * 128;
    const int row_b0 = bn * 128;

    int cr[4], cc[4];
#pragma unroll
    for (int i = 0; i < 4; ++i) {
        int c = tid + 256 * i;
        cr[i] = c >> 3;
        cc[i] = (c & 7) << 3;
    }

    float4 pa[8];
    int4   pbi[8];
    uint2  pb8[4];

    auto load_tile = [&](int kt) {
        int k0 = kt * 64;
#pragma unroll
        for (int i = 0; i < 4; ++i) {
            const float* p = A + (size_t)(row_a0 + cr[i]) * K_DIM + k0 + cc[i];
            pa[2 * i]     = *(const float4*)p;
            pa[2 * i + 1] = *(const float4*)(p + 4);
        }
        if (wi32) {
            const int* w = (const int*)Wv;
#pragma unroll
            for (int i = 0; i < 4; ++i) {
                const int* p = w + (size_t)(row_b0 + cr[i]) * K_DIM + k0 + cc[i];
                pbi[2 * i]     = *(const int4*)p;
                pbi[2 * i + 1] = *(const int4*)(p + 4);
            }
        } else {
            const signed char* w = (const signed char*)Wv;
#pragma unroll
            for (int i = 0; i < 4; ++i) {
                const signed char* p = w + (size_t)(row_b0 + cr[i]) * K_DIM + k0 + cc[i];
                pb8[i] = *(const uint2*)p;
            }
        }
    };

    auto write_lds = [&]() {
#pragma unroll
        for (int i = 0; i < 4; ++i) {
            int off = (cr[i] * 128 + cc[i] * 2) ^ ((cr[i] & 7) << 4);
            half8 h;
            h[0] = (_Float16)pa[2 * i].x;
            h[1] = (_Float16)pa[2 * i].y;
            h[2] = (_Float16)pa[2 * i].z;
            h[3] = (_Float16)pa[2 * i].w;
            h[4] = (_Float16)pa[2 * i + 1].x;
            h[5] = (_Float16)pa[2 * i + 1].y;
            h[6] = (_Float16)pa[2 * i + 1].z;
            h[7] = (_Float16)pa[2 * i + 1].w;
            *(half8*)(Ash + off) = h;

            half8 g;
            if (wi32) {
                g[0] = (_Float16)pbi[2 * i].x;
                g[1] = (_Float16)pbi[2 * i].y;
                g[2] = (_Float16)pbi[2 * i].z;
                g[3] = (_Float16)pbi[2 * i].w;
                g[4] = (_Float16)pbi[2 * i + 1].x;
                g[5] = (_Float16)pbi[2 * i + 1].y;
                g[6] = (_Float16)pbi[2 * i + 1].z;
                g[7] = (_Float16)pbi[2 * i + 1].w;
            } else {
                unsigned x = pb8[i].x, y = pb8[i].y;
                g[0] = (_Float16)(int)(signed char)(x & 0xff);
                g[1] = (_Float16)(int)(signed char)((x >> 8) & 0xff);
                g[2] = (_Float16)(int)(signed char)((x >> 16) & 0xff);
                g[3] = (_Float16)(int)(signed char)(x >> 24);
                g[4] = (_Float16)(int)(signed char)(y & 0xff);
                g[5] = (_Float16)(int)(signed char)((y >> 8) & 0xff);
                g[6] = (_Float16)(int)(signed char)((y >> 16) & 0xff);
                g[7] = (_Float16)(int)(signed char)(y >> 24);
            }
            *(half8*)(Bsh + off) = g;
        }
    };

    f32x4 acc[4][4] = {};

    auto compute = [&]() {
#pragma unroll
        for (int ks = 0; ks < 2; ++ks) {
            half8 af[4], bfr[4];
#pragma unroll
            for (int m = 0; m < 4; ++m) {
                int row = wwm * 64 + m * 16 + r16;
                af[m] = *(const half8*)(Ash + ((row * 128 + ks * 64 + kq * 16) ^ swzl));
            }
#pragma unroll
            for (int n = 0; n < 4; ++n) {
                int row = wwn * 64 + n * 16 + r16;
                bfr[n] = *(const half8*)(Bsh + ((row * 128 + ks * 64 + kq * 16) ^ swzl));
            }
#pragma unroll
            for (int m = 0; m < 4; ++m)
#pragma unroll
                for (int n = 0; n < 4; ++n)
                    acc[m][n] = __builtin_amdgcn_mfma_f32_16x16x32_f16(af[m], bfr[n], acc[m][n], 0, 0, 0);
        }
    };

    load_tile(0);
#pragma unroll 1
    for (int kt = 0; kt < NT; ++kt) {
        if (kt) __syncthreads();
        write_lds();
        __syncthreads();
        if (kt + 1 < NT) load_tile(kt + 1);
        compute();
    }

#pragma unroll
    for (int n = 0; n < 4; ++n) {
        int col = row_b0 + wwn * 64 + n * 16 + r16;
        float s = scales[col];
        float b = bias[col];
#pragma unroll
        for (int m = 0; m < 4; ++m) {
            int row0 = row_a0 + wwm * 64 + m * 16 + kq * 4;
#pragma unroll
            for (int j = 0; j < 4; ++j) {
                out[(size_t)(row0 + j) * N_DIM + col] = acc[m][n][j] * s + b;
            }
        }
    }
}

extern "C" void kernel_launch(void* const* d_in, const int* in_sizes, int n_in,
                              void* d_out, int out_size, void* d_ws, size_t ws_size,
                              hipStream_t stream) {
    const float* A      = (const float*)d_in[0];
    const void*  W      = d_in[1];
    const float* scales = (const float*)d_in[2];
    const float* bias   = (const float*)d_in[3];
    float*       out    = (float*)d_out;

    const size_t needA = (size_t)M_DIM * K_DIM * 2;   // 64 MiB
    const size_t needW = (size_t)N_DIM * K_DIM * 2;   // 32 MiB

    if (ws_size >= needA + needW) {
        _Float16* Apack = (_Float16*)d_ws;
        _Float16* Wpack = (_Float16*)((char*)d_ws + needA);
        hipLaunchKernelGGL(prep_a, dim3(16384), dim3(256), 0, stream, A, Apack);
        hipLaunchKernelGGL(prep_w, dim3(8192), dim3(256), 0, stream, W, Wpack);
        hipLaunchKernelGGL(w8a16_gemm3, dim3(512), dim3(512), 0, stream,
                           Apack, Wpack, scales, bias, out);
    } else {
        hipLaunchKernelGGL(w8a16_gemm, dim3(2048), dim3(256), 0, stream,
                           A, W, scales, bias, out);
    }
}

// Round 6
// 200.158 us; speedup vs baseline: 3.3433x; 1.4765x over previous
//
#include <hip/hip_runtime.h>
#include <stdint.h>

typedef int   i32x4 __attribute__((ext_vector_type(4)));
typedef float f32x4 __attribute__((ext_vector_type(4)));
typedef _Float16 half8 __attribute__((ext_vector_type(8)));

#define M_DIM 8192
#define N_DIM 4096
#define K_DIM 4096
#define BM 256
#define BN 256
#define BK 64
#define NT (K_DIM / BK)            // 64
#define TILE_I8 16384              // one K-tile image: 256 rows x 64 k x 1B

#define GLOAD_LDS16(g, l)                                        \
    __builtin_amdgcn_global_load_lds(                            \
        (const __attribute__((address_space(1))) uint32_t*)(g),  \
        (__attribute__((address_space(3))) uint32_t*)(l), 16, 0, 0)

#define BARRIER()  asm volatile("s_barrier" ::: "memory")
#define WAIT_VM0() asm volatile("s_waitcnt vmcnt(0)" ::: "memory")

// In-image byte offset for (row, 16B-slot 0..3), row stride 64 B (64 int8).
// slot' = slot ^ (row>>1 & 3): spreads each kq-group's rows over all bank
// quads -> 2 addr/bank per wave ds_read_b128 (2-way is free, m136).
// Involution baked into pack-write AND LDS-read; global_load_lds stays linear.
__device__ __forceinline__ int img_off(int row, int slot) {
    return row * 64 + ((slot ^ ((row >> 1) & 3)) << 4);
}

// ---------------- prep_a: per-row quantize A fp32 -> int8, pack tiles ----------------
// One wave per row. Pass 1: row absmax (row is L1-resident after).
// Pass 2: quantize to int8 (exact 127 at rowmax), write 16B chunks into
// tile image (bm,kt) at (bm*NT+kt)*TILE_I8 + img_off(row&255, k>>4).
__global__ __launch_bounds__(256)
void prep_a(const float* __restrict__ A, signed char* __restrict__ Apack,
            float* __restrict__ Ascale) {
    const int wv   = threadIdx.x >> 6;
    const int lane = threadIdx.x & 63;
    const int r    = blockIdx.x * 4 + wv;          // 2048 blocks * 4 rows
    const float* row = A + (size_t)r * K_DIM;

    // pass 1: absmax
    float mx = 0.f;
#pragma unroll
    for (int p = 0; p < 16; ++p) {
        float4 v = *(const float4*)(row + p * 256 + lane * 4);
        mx = fmaxf(mx, fmaxf(fmaxf(fabsf(v.x), fabsf(v.y)),
                             fmaxf(fabsf(v.z), fabsf(v.w))));
    }
#pragma unroll
    for (int s = 1; s < 64; s <<= 1)
        mx = fmaxf(mx, __shfl_xor(mx, s, 64));

    float inv = mx > 0.f ? 127.f / mx : 0.f;
    if (lane == 0) Ascale[r] = mx * (1.f / 127.f);

    // pass 2: quantize, 16 contiguous elems per chunk (L1-hot reload)
    const int bm = r >> 8, rl = r & 255;
    signed char* tb = Apack + (size_t)bm * NT * TILE_I8;
#pragma unroll
    for (int g = 0; g < 4; ++g) {
        int col0 = g * 1024 + lane * 16;
        unsigned w[4];
#pragma unroll
        for (int q = 0; q < 4; ++q) {
            float4 v = *(const float4*)(row + col0 + q * 4);
            int a0 = (int)rintf(v.x * inv);
            int a1 = (int)rintf(v.y * inv);
            int a2 = (int)rintf(v.z * inv);
            int a3 = (int)rintf(v.w * inv);
            w[q] = (a0 & 255) | ((a1 & 255) << 8) | ((a2 & 255) << 16)
                 | ((unsigned)(a3 & 255) << 24);
        }
        int kt = col0 >> 6, k = col0 & 63;
        uint4 pk = make_uint4(w[0], w[1], w[2], w[3]);
        *(uint4*)(tb + (size_t)kt * TILE_I8 + img_off(rl, k >> 4)) = pk;
    }
}

// ---------------- prep_w: repack W int8 (or narrow int32) into tiles ----------------
__global__ __launch_bounds__(256)
void prep_w(const void* __restrict__ Wv, signed char* __restrict__ Wpack) {
    // probe element width: int32 buffer or raw int8?
    const int* wp = (const int*)Wv;
    bool wi32 = true;
#pragma unroll
    for (int i = 0; i < 16; ++i) {
        int v = wp[i];
        wi32 = wi32 && (v >= -128 && v <= 127);
    }
    int g = blockIdx.x * 256 + threadIdx.x;   // 1,048,576 chunks of 16
    int r = g >> 8;                           // row 0..4095
    int col0 = (g & 255) << 4;
    uint4 pk;
    if (wi32) {
        const int* p = (const int*)Wv + (size_t)r * K_DIM + col0;
        unsigned w[4];
#pragma unroll
        for (int q = 0; q < 4; ++q) {
            int4 v = *(const int4*)(p + q * 4);
            w[q] = (v.x & 255) | ((v.y & 255) << 8) | ((v.z & 255) << 16)
                 | ((unsigned)(v.w & 255) << 24);
        }
        pk = make_uint4(w[0], w[1], w[2], w[3]);
    } else {
        pk = *(const uint4*)((const signed char*)Wv + (size_t)r * K_DIM + col0);
    }
    int bn = r >> 8, rl = r & 255;
    int kt = col0 >> 6, k = col0 & 63;
    *(uint4*)(Wpack + (size_t)(bn * NT + kt) * TILE_I8 + img_off(rl, k >> 4)) = pk;
}

// ---------------- main GEMM: int8 MFMA, 256x256 tile, 1-barrier pipeline ----------------
// 8 waves (2M x 4N), 512 threads, wave tile 128x64, 64 KiB LDS (2-tile dbuf).
// Per K-tile per wave: 4 gload_lds (prefetch t+1) + 12 ds_read_b128 +
// 32 mfma_i32_16x16x64_i8 + vmcnt(0) + barrier. MFMA-pipe demand (~650
// cyc/wave) dominates LDS (~150 cyc) 4:1 -> 2 waves/SIMD keeps pipe fed.
__global__ __launch_bounds__(512, 2)
void w8a16_gemm_i8(const signed char* __restrict__ Apack,
                   const signed char* __restrict__ Wpack,
                   const float* __restrict__ Ascale,
                   const float* __restrict__ scales,
                   const float* __restrict__ bias,
                   float* __restrict__ out) {
    __shared__ char smem[65536];
    // layout: buf*32768 + (B ? 16384 : 0) + img_off

    const int tid  = threadIdx.x;
    const int lane = tid & 63;
    const int wv   = tid >> 6;     // 0..7
    const int wm   = wv >> 2;      // 0..1  (M half: 128 rows)
    const int wn   = wv & 3;       // 0..3  (N quarter: 64 cols)
    const int r16  = lane & 15;
    const int kq   = lane >> 4;

    // XCD-aware bijective swizzle (512 % 8 == 0)
    int bid = blockIdx.x;
    int swz = (bid & 7) * 64 + (bid >> 3);
    int bm = swz >> 4;             // 0..31
    int bn = swz & 15;             // 0..15

    const char* Abase = (const char*)Apack + (size_t)bm * NT * TILE_I8 + tid * 16;
    const char* Bbase = (const char*)Wpack + (size_t)bn * NT * TILE_I8 + tid * 16;

    auto issueT = [&](int kt_src, int buf) {
        const char* ga = Abase + (size_t)kt_src * TILE_I8;
        const char* gb = Bbase + (size_t)kt_src * TILE_I8;
        char* la = smem + buf * 32768 + tid * 16;
        char* lb = la + 16384;
        GLOAD_LDS16(ga,        la);
        GLOAD_LDS16(ga + 8192, la + 8192);
        GLOAD_LDS16(gb,        lb);
        GLOAD_LDS16(gb + 8192, lb + 8192);
    };

    i32x4 af[4], bf[4];
    i32x4 acc[8][4] = {};

    auto loadA = [&](int buf, int mh) {
#pragma unroll
        for (int m = 0; m < 4; ++m) {
            int row = wm * 128 + mh * 64 + m * 16 + r16;
            af[m] = *(const i32x4*)(smem + buf * 32768 + img_off(row, kq));
        }
    };
    auto loadB = [&](int buf) {
#pragma unroll
        for (int n = 0; n < 4; ++n) {
            int row = wn * 64 + n * 16 + r16;
            bf[n] = *(const i32x4*)(smem + buf * 32768 + 16384 + img_off(row, kq));
        }
    };
    auto mmac4 = [&](i32x4 (*ac)[4]) {
#pragma unroll
        for (int n = 0; n < 4; ++n)
#pragma unroll
            for (int m = 0; m < 4; ++m)
                ac[m][n] = __builtin_amdgcn_mfma_i32_16x16x64_i8(af[m], bf[n], ac[m][n], 0, 0, 0);
    };

    // prologue: stage K-tile 0 into buf0
    issueT(0, 0);
    WAIT_VM0();
    BARRIER();

#pragma unroll 1
    for (int t = 0; t < NT; ++t) {
        int buf  = t & 1;
        int nbuf = buf ^ 1;

        if (t + 1 < NT) issueT(t + 1, nbuf);   // prefetch: max issue->wait dist

        loadA(buf, 0);
        loadB(buf);
        __builtin_amdgcn_s_setprio(1);
        mmac4(&acc[0]);
        __builtin_amdgcn_s_setprio(0);

        loadA(buf, 1);
        __builtin_amdgcn_s_setprio(1);
        mmac4(&acc[4]);
        __builtin_amdgcn_s_setprio(0);

        WAIT_VM0();   // own t+1 loads landed (covered by ~full compute block)
        BARRIER();    // all waves' loads visible; all buf reads done
    }

    // ---- epilogue: out = acc * ascale[row] * scales[col] + bias[col] ----
    float sc[4], bs[4];
#pragma unroll
    for (int n = 0; n < 4; ++n) {
        int col = bn * BN + wn * 64 + n * 16 + r16;
        sc[n] = scales[col];
        bs[n] = bias[col];
    }
#pragma unroll
    for (int mi = 0; mi < 8; ++mi) {
        int row0 = bm * BM + wm * 128 + mi * 16 + kq * 4;
#pragma unroll
        for (int j = 0; j < 4; ++j) {
            int row = row0 + j;
            float as_ = Ascale[row];
#pragma unroll
            for (int n = 0; n < 4; ++n) {
                int col = bn * BN + wn * 64 + n * 16 + r16;
                out[(size_t)row * N_DIM + col] =
                    (float)acc[mi][n][j] * (as_ * sc[n]) + bs[n];
            }
        }
    }
}

// ---------------- fallback (reg-staged fp16, no workspace needed) ----------------
__global__ __launch_bounds__(256, 2)
void w8a16_gemm(const float* __restrict__ A,
                const void* __restrict__ Wv,
                const float* __restrict__ scales,
                const float* __restrict__ bias,
                float* __restrict__ out) {
    __shared__ char smem[2 * 128 * 64 * 2];
    char* Ash = smem;
    char* Bsh = smem + 128 * 64 * 2;

    const int* wprobe = (const int*)Wv;
    bool wi32 = true;
#pragma unroll
    for (int i = 0; i < 16; ++i) {
        int v = wprobe[i];
        wi32 = wi32 && (v >= -128 && v <= 127);
    }

    const int tid  = threadIdx.x;
    const int lane = tid & 63;
    const int wv   = tid >> 6;
    const int wwm  = wv >> 1;
    const int wwn  = wv & 1;
    const int r16  = lane & 15;
    const int kq   = lane >> 4;
    const int swzl = (r16 & 7) << 4;

    int bid = blockIdx.x;
    int swz = (bid & 7) * 256 + (bid >> 3);
    int bm = swz / 32;
    int bn = swz % 32;

    const int row_a0 = bm * 128;
    const int row_b0 = bn * 128;

    int cr[4], cc[4];
#pragma unroll
    for (int i = 0; i < 4; ++i) {
        int c = tid + 256 * i;
        cr[i] = c >> 3;
        cc[i] = (c & 7) << 3;
    }

    float4 pa[8];
    int4   pbi[8];
    uint2  pb8[4];

    auto load_tile = [&](int kt) {
        int k0 = kt * 64;
#pragma unroll
        for (int i = 0; i < 4; ++i) {
            const float* p = A + (size_t)(row_a0 + cr[i]) * K_DIM + k0 + cc[i];
            pa[2 * i]     = *(const float4*)p;
            pa[2 * i + 1] = *(const float4*)(p + 4);
        }
        if (wi32) {
            const int* w = (const int*)Wv;
#pragma unroll
            for (int i = 0; i < 4; ++i) {
                const int* p = w + (size_t)(row_b0 + cr[i]) * K_DIM + k0 + cc[i];
                pbi[2 * i]     = *(const int4*)p;
                pbi[2 * i + 1] = *(const int4*)(p + 4);
            }
        } else {
            const signed char* w = (const signed char*)Wv;
#pragma unroll
            for (int i = 0; i < 4; ++i) {
                const signed char* p = w + (size_t)(row_b0 + cr[i]) * K_DIM + k0 + cc[i];
                pb8[i] = *(const uint2*)p;
            }
        }
    };

    auto write_lds = [&]() {
#pragma unroll
        for (int i = 0; i < 4; ++i) {
            int off = (cr[i] * 128 + cc[i] * 2) ^ ((cr[i] & 7) << 4);
            half8 h;
            h[0] = (_Float16)pa[2 * i].x;
            h[1] = (_Float16)pa[2 * i].y;
            h[2] = (_Float16)pa[2 * i].z;
            h[3] = (_Float16)pa[2 * i].w;
            h[4] = (_Float16)pa[2 * i + 1].x;
            h[5] = (_Float16)pa[2 * i + 1].y;
            h[6] = (_Float16)pa[2 * i + 1].z;
            h[7] = (_Float16)pa[2 * i + 1].w;
            *(half8*)(Ash + off) = h;

            half8 g;
            if (wi32) {
                g[0] = (_Float16)pbi[2 * i].x;
                g[1] = (_Float16)pbi[2 * i].y;
                g[2] = (_Float16)pbi[2 * i].z;
                g[3] = (_Float16)pbi[2 * i].w;
                g[4] = (_Float16)pbi[2 * i + 1].x;
                g[5] = (_Float16)pbi[2 * i + 1].y;
                g[6] = (_Float16)pbi[2 * i + 1].z;
                g[7] = (_Float16)pbi[2 * i + 1].w;
            } else {
                unsigned x = pb8[i].x, y = pb8[i].y;
                g[0] = (_Float16)(int)(signed char)(x & 0xff);
                g[1] = (_Float16)(int)(signed char)((x >> 8) & 0xff);
                g[2] = (_Float16)(int)(signed char)((x >> 16) & 0xff);
                g[3] = (_Float16)(int)(signed char)(x >> 24);
                g[4] = (_Float16)(int)(signed char)(y & 0xff);
                g[5] = (_Float16)(int)(signed char)((y >> 8) & 0xff);
                g[6] = (_Float16)(int)(signed char)((y >> 16) & 0xff);
                g[7] = (_Float16)(int)(signed char)(y >> 24);
            }
            *(half8*)(Bsh + off) = g;
        }
    };

    f32x4 acc[4][4] = {};

    auto compute = [&]() {
#pragma unroll
        for (int ks = 0; ks < 2; ++ks) {
            half8 af[4], bfr[4];
#pragma unroll
            for (int m = 0; m < 4; ++m) {
                int row = wwm * 64 + m * 16 + r16;
                af[m] = *(const half8*)(Ash + ((row * 128 + ks * 64 + kq * 16) ^ swzl));
            }
#pragma unroll
            for (int n = 0; n < 4; ++n) {
                int row = wwn * 64 + n * 16 + r16;
                bfr[n] = *(const half8*)(Bsh + ((row * 128 + ks * 64 + kq * 16) ^ swzl));
            }
#pragma unroll
            for (int m = 0; m < 4; ++m)
#pragma unroll
                for (int n = 0; n < 4; ++n)
                    acc[m][n] = __builtin_amdgcn_mfma_f32_16x16x32_f16(af[m], bfr[n], acc[m][n], 0, 0, 0);
        }
    };

    load_tile(0);
#pragma unroll 1
    for (int kt = 0; kt < NT; ++kt) {
        if (kt) __syncthreads();
        write_lds();
        __syncthreads();
        if (kt + 1 < NT) load_tile(kt + 1);
        compute();
    }

#pragma unroll
    for (int n = 0; n < 4; ++n) {
        int col = row_b0 + wwn * 64 + n * 16 + r16;
        float s = scales[col];
        float b = bias[col];
#pragma unroll
        for (int m = 0; m < 4; ++m) {
            int row0 = row_a0 + wwm * 64 + m * 16 + kq * 4;
#pragma unroll
            for (int j = 0; j < 4; ++j) {
                out[(size_t)(row0 + j) * N_DIM + col] = acc[m][n][j] * s + b;
            }
        }
    }
}

extern "C" void kernel_launch(void* const* d_in, const int* in_sizes, int n_in,
                              void* d_out, int out_size, void* d_ws, size_t ws_size,
                              hipStream_t stream) {
    const float* A      = (const float*)d_in[0];
    const void*  W      = d_in[1];
    const float* scales = (const float*)d_in[2];
    const float* bias   = (const float*)d_in[3];
    float*       out    = (float*)d_out;

    const size_t needA = (size_t)M_DIM * K_DIM;        // 32 MiB int8
    const size_t needW = (size_t)N_DIM * K_DIM;        // 16 MiB int8
    const size_t needS = (size_t)M_DIM * sizeof(float);

    if (ws_size >= needA + needW + needS) {
        signed char* Apack = (signed char*)d_ws;
        signed char* Wpack = (signed char*)d_ws + needA;
        float*       Asc   = (float*)((char*)d_ws + needA + needW);
        hipLaunchKernelGGL(prep_a, dim3(2048), dim3(256), 0, stream, A, Apack, Asc);
        hipLaunchKernelGGL(prep_w, dim3(4096), dim3(256), 0, stream, W, Wpack);
        hipLaunchKernelGGL(w8a16_gemm_i8, dim3(512), dim3(512), 0, stream,
                           Apack, Wpack, Asc, scales, bias, out);
    } else {
        hipLaunchKernelGGL(w8a16_gemm, dim3(2048), dim3(256), 0, stream,
                           A, W, scales, bias, out);
    }
}